// Round 12
// baseline (128.347 us; speedup 1.0000x reference)
//
#include <hip/hip_runtime.h>
#include <hip/hip_fp16.h>
#include <stdint.h>

#define NB  32
#define NLQ 128
#define NLK 4096
#define NDK 256
#define NDV 256
#define KT  16
#define SPLITS 8
#define MINSPLITS 4

typedef _Float16 f16;
typedef _Float16 f16x4 __attribute__((ext_vector_type(4)));
typedef _Float16 f16x8 __attribute__((ext_vector_type(8)));
typedef float    f32x4 __attribute__((ext_vector_type(4)));

// ---------------- Kernel 1: per (key-split s, batch b, q-half) partials -----
// 8 waves = (4 q-tiles x 2 dv-halves); wave = 16 queries x 128 dv.
// r11 established: total regs (arch+acc) <= 128 -> 2 blocks/CU, 38.8% occ,
// and FETCH is already at the unique floor -> the lever is achieved HBM BW.
// This round: V staged through LDS (r5-proven swizzle, 0 conflicts) so ALL
// HBM traffic is wide coalesced dwordx4 prefetches (K+V = 4/thread/tile in
// flight through compute) instead of 32 scalar V loads/thread/tile clogging
// the VMEM pipe; PV fragments come from LDS. XCD remap: qz-pair of slice s
// at x in {s, s+8} -> same XCD (grid.y stride 16 preserves id%8) -> twin
// block's re-read hits that XCD's L2 instead of L3.
__global__ __launch_bounds__(512) void fvta_part1(
    const float* __restrict__ q_, const float* __restrict__ k_,
    const float* __restrict__ v_, const int* __restrict__ mask_,
    f16* __restrict__ accw, float* __restrict__ mlw)
{
    __shared__ __align__(16) f16 KA[2][KT * NDK];   // 16 KB
    __shared__ __align__(16) f16 VA[2][KT * NDV];   // 16 KB
    __shared__ __align__(16) f16 QA[64 * NDK];      // 32 KB
    __shared__ int MK[NLK / MINSPLITS];             // 4 KB

    const int tid = threadIdx.x, w = tid >> 6, lane = tid & 63;
    const int l15 = lane & 15, lhi = lane >> 4;
    const int qsub = w >> 1;          // 0..3: q-tile within block
    const int dvh  = w & 1;           // 0..1: dv half
    const int x = blockIdx.x, b = blockIdx.y;
    const int S = gridDim.x >> 1;
    // XCD remap when S==8: pair {s, s+8} shares an XCD; else simple split.
    const int s  = (S == 8) ? (x & 7) : (x >> 1);
    const int qz = (S == 8) ? (x >> 3) : (x & 1);
    const int slice = NLK / S, nt = slice / KT, kbase = s * slice;
    const float NEG = -__builtin_inff();

    const float* kb = k_ + ((size_t)b * NLK + kbase) * NDK;
    const float* vb = v_ + ((size_t)b * NLK + kbase) * NDV;
    const int*   mb = mask_ + b * NLK + kbase;

    // ---- masks for the whole slice -> LDS
    for (int i = tid; i < slice; i += 512) MK[i] = mb[i];

    // ---- stage Q rows [qz*64, qz*64+64) f32->f16, same XOR swizzle as K
    {
        const float* qsrc = q_ + ((size_t)b * NLQ + qz * 64) * NDK;
        #pragma unroll
        for (int r = 0; r < 8; ++r) {
            const int idx = r * 512 + tid;        // 0..4095
            const int qq  = idx >> 6;             // row 0..63
            const int d   = (idx & 63) * 4;
            f32x4 xv = *(const f32x4*)(qsrc + qq * NDK + d);
            f16x4 hh; hh[0]=(f16)xv[0]; hh[1]=(f16)xv[1]; hh[2]=(f16)xv[2]; hh[3]=(f16)xv[3];
            *(f16x4*)(QA + qq * NDK + (d ^ ((qq & 15) << 3))) = hh;
        }
    }

    f32x4 accu[8];    // O[q=lhi*4+j][dv = dvh*128 + d*16 + l15]  (32 AGPR)
    #pragma unroll
    for (int i = 0; i < 8; ++i) accu[i] = (f32x4){0.f, 0.f, 0.f, 0.f};
    float m_run = NEG, l_run = 0.f;

    f32x4 ks[2], vs[2];   // staged K/V f32 for next tile (16x256 / 512 thr)

    auto stage = [&](f16* KAb, f16* VAb) {
        #pragma unroll
        for (int r = 0; r < 2; ++r) {
            const int idx = r * 512 + tid;
            const int kk  = idx >> 6;
            const int d   = (idx & 63) * 4;
            const int e   = kk * NDK + (d ^ (kk << 3));   // kk < 16
            f32x4 xv = ks[r];
            f16x4 hh; hh[0]=(f16)xv[0]; hh[1]=(f16)xv[1]; hh[2]=(f16)xv[2]; hh[3]=(f16)xv[3];
            *(f16x4*)(KAb + e) = hh;
            f32x4 yv = vs[r];
            f16x4 gg; gg[0]=(f16)yv[0]; gg[1]=(f16)yv[1]; gg[2]=(f16)yv[2]; gg[3]=(f16)yv[3];
            *(f16x4*)(VAb + e) = gg;
        }
    };

    // prologue: load + stage tile 0
    #pragma unroll
    for (int r = 0; r < 2; ++r) {
        ks[r] = *(const f32x4*)(kb + (r * 512 + tid) * 4);
        vs[r] = *(const f32x4*)(vb + (r * 512 + tid) * 4);
    }
    stage(KA[0], VA[0]);
    __syncthreads();

    const int swz = l15 << 3;   // row&15 == l15 for Q and K reads

    for (int t = 0; t < nt; ++t) {
        const int cur = t & 1;
        if (t + 1 < nt) {   // prefetch next K+V tiles (in flight thru compute)
            const float* ksrc = kb + (size_t)(t + 1) * KT * NDK;
            const float* vsrc = vb + (size_t)(t + 1) * KT * NDV;
            #pragma unroll
            for (int r = 0; r < 2; ++r) {
                ks[r] = *(const f32x4*)(ksrc + (r * 512 + tid) * 4);
                vs[r] = *(const f32x4*)(vsrc + (r * 512 + tid) * 4);
            }
        }
        const int k0 = t * KT;

        // ---- QK^T over 16 keys (A = K rows, B = Q rows, both from LDS)
        f32x4 s4 = (f32x4){0.f,0.f,0.f,0.f};
        {
            const f16* kp = &KA[cur][l15 * NDK];
            const f16* qp = &QA[(qsub * 16 + l15) * NDK];
            #pragma unroll
            for (int kd = 0; kd < 8; ++kd) {
                const int col = (kd * 32 + lhi * 8) ^ swz;
                f16x8 kf = *(const f16x8*)(kp + col);
                f16x8 qv = *(const f16x8*)(qp + col);
                s4 = __builtin_amdgcn_mfma_f32_16x16x32_f16(kf, qv, s4, 0, 0, 0);
            }
        }
        // s4[j] = S[key=k0+lhi*4+j][q=l15]

        // ---- mask -> -inf (from LDS), online softmax over 16 keys
        const int4 m4 = *(const int4*)(MK + k0 + lhi * 4);
        float sa[4];
        sa[0] = m4.x ? NEG : s4[0]; sa[1] = m4.y ? NEG : s4[1];
        sa[2] = m4.z ? NEG : s4[2]; sa[3] = m4.w ? NEG : s4[3];

        float tmax = fmaxf(fmaxf(sa[0], sa[1]), fmaxf(sa[2], sa[3]));
        tmax = fmaxf(tmax, __shfl_xor(tmax, 16, 64));
        tmax = fmaxf(tmax, __shfl_xor(tmax, 32, 64));
        const float mnew = fmaxf(m_run, tmax);
        const bool  dead = (mnew == NEG);
        const float scale = dead ? 1.f : __expf(m_run - mnew);
        float p4[4];
        #pragma unroll
        for (int j = 0; j < 4; ++j) p4[j] = dead ? 0.f : __expf(sa[j] - mnew);
        float ps = (p4[0] + p4[1]) + (p4[2] + p4[3]);
        ps += __shfl_xor(ps, 16, 64);
        ps += __shfl_xor(ps, 32, 64);
        l_run = l_run * scale + ps;
        m_run = mnew;

        f16x4 pa;
        pa[0]=(f16)p4[0]; pa[1]=(f16)p4[1]; pa[2]=(f16)p4[2]; pa[3]=(f16)p4[3];

        if (!__all(scale == 1.f)) {
            float scj[4];
            #pragma unroll
            for (int j = 0; j < 4; ++j) scj[j] = __shfl(scale, lhi * 4 + j, 64);
            #pragma unroll
            for (int d = 0; d < 8; ++d) {
                accu[d][0] *= scj[0]; accu[d][1] *= scj[1];
                accu[d][2] *= scj[2]; accu[d][3] *= scj[3];
            }
        }

        // ---- PV: B frag = V[row=lhi*4+j][dv=dvh*128+d*16+l15] from LDS
        // (r5-proven swizzled u16 reads, 0 conflicts measured).
        {
            const f16* VL = &VA[cur][0];
            #pragma unroll
            for (int dg = 0; dg < 2; ++dg) {
                #pragma unroll
                for (int dd = 0; dd < 4; ++dd) {
                    f16x4 vf;
                    #pragma unroll
                    for (int j = 0; j < 4; ++j) {
                        const int rr  = lhi * 4 + j;           // tile row 0..15
                        const int col = (dvh * 128 + (dg * 4 + dd) * 16 + l15)
                                        ^ (rr << 3);
                        vf[j] = VL[rr * NDV + col];
                    }
                    accu[dg * 4 + dd] = __builtin_amdgcn_mfma_f32_16x16x16f16(
                        pa, vf, accu[dg * 4 + dd], 0, 0, 0);
                }
            }
        }

        if (t + 1 < nt) stage(KA[cur ^ 1], VA[cur ^ 1]);
        __syncthreads();
    }

    // ---- write partials {acc (f16), m, l (f32)} to workspace
    const size_t base = (size_t)(b * S + s) * NLQ + qz * 64 + qsub * 16;
    #pragma unroll
    for (int j = 0; j < 4; ++j) {
        f16* dst = accw + (base + lhi * 4 + j) * NDV + dvh * 128 + l15;
        #pragma unroll
        for (int d = 0; d < 8; ++d) dst[d * 16] = (f16)accu[d][j];
    }
    if (dvh == 0 && lane < 16) {
        mlw[(base + lane) * 2]     = m_run;
        mlw[(base + lane) * 2 + 1] = l_run;
    }
}

// ---------------- Kernel 2: merge key-splits, q-length mask, mean ----------
// 8 queries per block (512 blocks).
__global__ __launch_bounds__(256) void fvta_merge(
    const f16* __restrict__ accw, const float* __restrict__ mlw,
    const int* __restrict__ qlen_, float* __restrict__ out_, int S)
{
    __shared__ float fac[8][SPLITS + 1];
    const int qc = blockIdx.x, b = blockIdx.y, tid = threadIdx.x;
    const int len = qlen_[b];
    const float NEG = -__builtin_inff();

    if (tid < 8) {
        const int q = qc * 8 + tid;
        if (q < len) {
            float gm = NEG;
            for (int ss = 0; ss < S; ++ss)
                gm = fmaxf(gm, mlw[((size_t)(b * S + ss) * NLQ + q) * 2]);
            float L = 0.f;
            for (int ss = 0; ss < S; ++ss) {
                const float m = mlw[((size_t)(b * S + ss) * NLQ + q) * 2];
                const float l = mlw[((size_t)(b * S + ss) * NLQ + q) * 2 + 1];
                if (m != NEG) L += l * __expf(m - gm);
            }
            for (int ss = 0; ss < S; ++ss) {
                const float m = mlw[((size_t)(b * S + ss) * NLQ + q) * 2];
                fac[tid][ss] = (gm != NEG && L > 0.f && m != NEG)
                             ? __expf(m - gm) / L : 0.f;
            }
        } else {
            for (int ss = 0; ss < S; ++ss) fac[tid][ss] = 0.f;
        }
    }
    __syncthreads();

    float sum = 0.f;
    for (int qq = 0; qq < 8; ++qq) {
        const int q = qc * 8 + qq;
        for (int ss = 0; ss < S; ++ss) {
            const float f = fac[qq][ss];
            if (f != 0.f)
                sum += (float)accw[((size_t)(b * S + ss) * NLQ + q) * NDV + tid] * f;
        }
    }
    atomicAdd(&out_[b * NDV + tid], sum * (1.f / NLQ));
}

extern "C" void kernel_launch(void* const* d_in, const int* in_sizes, int n_in,
                              void* d_out, int out_size, void* d_ws, size_t ws_size,
                              hipStream_t stream) {
    const float* q    = (const float*)d_in[0];
    const int*   qlen = (const int*)d_in[1];
    const float* k    = (const float*)d_in[2];
    const float* v    = (const float*)d_in[3];
    const int*   mask = (const int*)d_in[4];
    float* out = (float*)d_out;

    int S = SPLITS;   // auto-halve if ws is small (MK sized for S>=MINSPLITS)
    while (S > MINSPLITS &&
           ((size_t)NB * S * NLQ * NDV * 2 + (size_t)NB * S * NLQ * 8) > ws_size)
        S >>= 1;
    f16*   accw = (f16*)d_ws;
    float* mlw  = (float*)((char*)d_ws + (size_t)NB * S * NLQ * NDV * 2);

    hipMemsetAsync(out, 0, (size_t)out_size * sizeof(float), stream);
    dim3 g1(2 * S, NB);   // x = (s | qz<<3) when S==8: qz-pair on same XCD
    fvta_part1<<<g1, 512, 0, stream>>>(q, k, v, mask, accw, mlw);
    dim3 g2(NLQ / 8, NB);
    fvta_merge<<<g2, 256, 0, stream>>>(accw, mlw, qlen, out, S);
}

// Round 13
// 127.442 us; speedup vs baseline: 1.0071x; 1.0071x over previous
//
#include <hip/hip_runtime.h>
#include <hip/hip_fp16.h>
#include <stdint.h>

#define NB  32
#define NLQ 128
#define NLK 4096
#define NDK 256
#define NDV 256
#define KT  32
#define SPLITS 8
#define MINSPLITS 4

typedef _Float16 f16;
typedef _Float16 f16x4 __attribute__((ext_vector_type(4)));
typedef _Float16 f16x8 __attribute__((ext_vector_type(8)));
typedef float    f32x4 __attribute__((ext_vector_type(4)));

// ---------------- Kernel 1: per (key-split s, batch b, q-half) partials -----
// 8 waves = (4 q-tiles x 2 dv-halves); wave = 16 queries x 128 dv.
// r12 post-mortem: warm replays run at cold speed -> NOT HBM-bound; the cost
// is ~3000 cyc/tile of barrier-drain + exposed-latency fixed cost, x nt.
// This round: KT=32 (nt=16, half the barrier events, 2x compute per tile to
// cover V-load latency) on the r11 skeleton (V direct-global keeps arch regs
// ~85; +32 acc <= 128 so 2 blocks/CU is retained). Defer-max (THR=8) skips
// the 36-VALU rescale on most tiles; partials written NORMALIZED (accu/l,
// f16-safe since P <= e^8 would otherwise overflow the raw sum).
__global__ __launch_bounds__(512) void fvta_part1(
    const float* __restrict__ q_, const float* __restrict__ k_,
    const float* __restrict__ v_, const int* __restrict__ mask_,
    f16* __restrict__ accw, float* __restrict__ mlw)
{
    __shared__ __align__(16) f16 KA[2][KT * NDK];   // 32 KB
    __shared__ __align__(16) f16 QA[64 * NDK];      // 32 KB
    __shared__ int MK[NLK / MINSPLITS];             // 4 KB

    const int tid = threadIdx.x, w = tid >> 6, lane = tid & 63;
    const int l15 = lane & 15, lhi = lane >> 4;
    const int qsub = w >> 1;          // 0..3: q-tile within block
    const int dvh  = w & 1;           // 0..1: dv half
    const int x = blockIdx.x, b = blockIdx.y;
    const int S = gridDim.x >> 1;
    const int s = x >> 1, qz = x & 1; // qz-pairs adjacent in dispatch order
    const int slice = NLK / S, nt = slice / KT, kbase = s * slice;
    const float NEG = -__builtin_inff();

    const float* kb = k_ + ((size_t)b * NLK + kbase) * NDK;
    const float* vb = v_ + ((size_t)b * NLK + kbase) * NDV;
    const int*   mb = mask_ + b * NLK + kbase;

    // ---- masks for the whole slice -> LDS
    for (int i = tid; i < slice; i += 512) MK[i] = mb[i];

    // ---- stage Q rows [qz*64, qz*64+64) f32->f16, XOR swizzle (as K)
    {
        const float* qsrc = q_ + ((size_t)b * NLQ + qz * 64) * NDK;
        #pragma unroll
        for (int r = 0; r < 8; ++r) {
            const int idx = r * 512 + tid;        // 0..4095
            const int qq  = idx >> 6;             // row 0..63
            const int d   = (idx & 63) * 4;
            f32x4 xv = *(const f32x4*)(qsrc + qq * NDK + d);
            f16x4 hh; hh[0]=(f16)xv[0]; hh[1]=(f16)xv[1]; hh[2]=(f16)xv[2]; hh[3]=(f16)xv[3];
            *(f16x4*)(QA + qq * NDK + (d ^ ((qq & 15) << 3))) = hh;
        }
    }

    f32x4 accu[8];    // O[q=lhi*4+j][dv = dvh*128 + d*16 + l15]  (32 AGPR)
    #pragma unroll
    for (int i = 0; i < 8; ++i) accu[i] = (f32x4){0.f, 0.f, 0.f, 0.f};
    float m_run = NEG, l_run = 0.f;

    f32x4 ks[4];   // staged K f32 for next tile (32x256 f32 / 512 threads)

    auto stage = [&](f16* KAb) {
        #pragma unroll
        for (int r = 0; r < 4; ++r) {
            const int idx = r * 512 + tid;        // 0..2047
            const int kk  = idx >> 6;             // 0..31
            const int d   = (idx & 63) * 4;
            const int e   = kk * NDK + (d ^ ((kk & 15) << 3));
            f32x4 xv = ks[r];
            f16x4 hh; hh[0]=(f16)xv[0]; hh[1]=(f16)xv[1]; hh[2]=(f16)xv[2]; hh[3]=(f16)xv[3];
            *(f16x4*)(KAb + e) = hh;
        }
    };

    // prologue: load + stage K tile 0
    #pragma unroll
    for (int r = 0; r < 4; ++r)
        ks[r] = *(const f32x4*)(kb + (r * 512 + tid) * 4);
    stage(KA[0]);
    __syncthreads();

    const int swz = l15 << 3;   // row&15 == l15 for Q and both K halves

    for (int t = 0; t < nt; ++t) {
        const int cur = t & 1;
        if (t + 1 < nt) {   // prefetch next K tile (in flight through compute)
            const float* ksrc = kb + (size_t)(t + 1) * KT * NDK;
            #pragma unroll
            for (int r = 0; r < 4; ++r)
                ks[r] = *(const f32x4*)(ksrc + (r * 512 + tid) * 4);
        }
        const int k0 = t * KT;

        // ---- QK^T, both 16-key halves (A = K rows, B = Q rows, from LDS)
        f32x4 s4a = (f32x4){0.f,0.f,0.f,0.f}, s4b = s4a;
        {
            const f16* k0p = &KA[cur][(0 * 16 + l15) * NDK];
            const f16* k1p = &KA[cur][(1 * 16 + l15) * NDK];
            const f16* qp  = &QA[(qsub * 16 + l15) * NDK];
            #pragma unroll
            for (int kd = 0; kd < 8; ++kd) {
                const int col = (kd * 32 + lhi * 8) ^ swz;
                f16x8 qv  = *(const f16x8*)(qp + col);
                f16x8 kfa = *(const f16x8*)(k0p + col);
                s4a = __builtin_amdgcn_mfma_f32_16x16x32_f16(kfa, qv, s4a, 0, 0, 0);
                f16x8 kfb = *(const f16x8*)(k1p + col);
                s4b = __builtin_amdgcn_mfma_f32_16x16x32_f16(kfb, qv, s4b, 0, 0, 0);
            }
        }
        // s4a[j] = S[key=k0+lhi*4+j][q=l15], s4b[j] = S[key=k0+16+lhi*4+j][q]

        // ---- mask -> -inf (LDS), online softmax over 32 keys, defer-max
        const int4 m4a = *(const int4*)(MK + k0 + lhi * 4);
        const int4 m4b = *(const int4*)(MK + k0 + 16 + lhi * 4);
        float sa[4], sb[4];
        sa[0] = m4a.x ? NEG : s4a[0]; sa[1] = m4a.y ? NEG : s4a[1];
        sa[2] = m4a.z ? NEG : s4a[2]; sa[3] = m4a.w ? NEG : s4a[3];
        sb[0] = m4b.x ? NEG : s4b[0]; sb[1] = m4b.y ? NEG : s4b[1];
        sb[2] = m4b.z ? NEG : s4b[2]; sb[3] = m4b.w ? NEG : s4b[3];

        float tmax = fmaxf(fmaxf(fmaxf(sa[0], sa[1]), fmaxf(sa[2], sa[3])),
                           fmaxf(fmaxf(sb[0], sb[1]), fmaxf(sb[2], sb[3])));
        tmax = fmaxf(tmax, __shfl_xor(tmax, 16, 64));
        tmax = fmaxf(tmax, __shfl_xor(tmax, 32, 64));

        // defer-max: keep m_run unless tile max exceeds it by >8 (P <= e^8)
        const bool defer = (m_run != NEG) && __all(tmax - m_run <= 8.f);
        if (!defer) {
            const float mnew = fmaxf(m_run, tmax);
            if (mnew != NEG) {
                const float scale = (m_run == NEG) ? 0.f : __expf(m_run - mnew);
                float scj[4];
                #pragma unroll
                for (int j = 0; j < 4; ++j) scj[j] = __shfl(scale, lhi * 4 + j, 64);
                #pragma unroll
                for (int d = 0; d < 8; ++d) {
                    accu[d][0] *= scj[0]; accu[d][1] *= scj[1];
                    accu[d][2] *= scj[2]; accu[d][3] *= scj[3];
                }
                l_run *= scale;
                m_run = mnew;
            }
        }

        float p4a[4], p4b[4];
        if (m_run == NEG) {   // everything masked so far
            #pragma unroll
            for (int j = 0; j < 4; ++j) { p4a[j] = 0.f; p4b[j] = 0.f; }
        } else {
            #pragma unroll
            for (int j = 0; j < 4; ++j) {
                p4a[j] = __expf(sa[j] - m_run);   // exp(-inf)=0 for masked
                p4b[j] = __expf(sb[j] - m_run);
            }
        }
        float ps = (p4a[0] + p4a[1]) + (p4a[2] + p4a[3])
                 + (p4b[0] + p4b[1]) + (p4b[2] + p4b[3]);
        ps += __shfl_xor(ps, 16, 64);
        ps += __shfl_xor(ps, 32, 64);
        l_run += ps;

        f16x4 pa, pb;
        pa[0]=(f16)p4a[0]; pa[1]=(f16)p4a[1]; pa[2]=(f16)p4a[2]; pa[3]=(f16)p4a[3];
        pb[0]=(f16)p4b[0]; pb[1]=(f16)p4b[1]; pb[2]=(f16)p4b[2]; pb[3]=(f16)p4b[3];

        // ---- PV: B frag = V[row][dv=dvh*128+d*16+l15], f32 direct global
        {
            #pragma unroll
            for (int h = 0; h < 2; ++h) {
                const f16x4 pfrag = h ? pb : pa;
                const float* vr = vb + (size_t)(k0 + h * 16 + lhi * 4) * NDV
                                + dvh * 128 + l15;
                #pragma unroll
                for (int dg = 0; dg < 2; ++dg) {
                    float tv[4][4];
                    #pragma unroll
                    for (int dd = 0; dd < 4; ++dd) {
                        const float* vc = vr + (dg * 4 + dd) * 16;
                        tv[dd][0] = vc[0];
                        tv[dd][1] = vc[1 * NDV];
                        tv[dd][2] = vc[2 * NDV];
                        tv[dd][3] = vc[3 * NDV];
                    }
                    #pragma unroll
                    for (int dd = 0; dd < 4; ++dd) {
                        f16x4 vf;
                        vf[0]=(f16)tv[dd][0]; vf[1]=(f16)tv[dd][1];
                        vf[2]=(f16)tv[dd][2]; vf[3]=(f16)tv[dd][3];
                        accu[dg * 4 + dd] = __builtin_amdgcn_mfma_f32_16x16x16f16(
                            pfrag, vf, accu[dg * 4 + dd], 0, 0, 0);
                    }
                }
            }
        }

        if (t + 1 < nt) stage(KA[cur ^ 1]);
        __syncthreads();
    }

    // ---- write NORMALIZED partials accu/l (f16-safe under defer-max)
    const float rl = (l_run > 0.f) ? 1.f / l_run : 0.f;
    float rlj[4];
    #pragma unroll
    for (int j = 0; j < 4; ++j) rlj[j] = __shfl(rl, lhi * 4 + j, 64);

    const size_t base = (size_t)(b * S + s) * NLQ + qz * 64 + qsub * 16;
    #pragma unroll
    for (int j = 0; j < 4; ++j) {
        f16* dst = accw + (base + lhi * 4 + j) * NDV + dvh * 128 + l15;
        #pragma unroll
        for (int d = 0; d < 8; ++d) dst[d * 16] = (f16)(accu[d][j] * rlj[j]);
    }
    if (dvh == 0 && lane < 16) {
        mlw[(base + lane) * 2]     = m_run;
        mlw[(base + lane) * 2 + 1] = l_run;
    }
}

// ---------------- Kernel 2: merge key-splits, q-length mask, mean ----------
// Partials are normalized: O = sum_ss accw_ss * (l_ss * exp(m_ss-gm) / L).
__global__ __launch_bounds__(256) void fvta_merge(
    const f16* __restrict__ accw, const float* __restrict__ mlw,
    const int* __restrict__ qlen_, float* __restrict__ out_, int S)
{
    __shared__ float fac[8][SPLITS + 1];
    const int qc = blockIdx.x, b = blockIdx.y, tid = threadIdx.x;
    const int len = qlen_[b];
    const float NEG = -__builtin_inff();

    if (tid < 8) {
        const int q = qc * 8 + tid;
        if (q < len) {
            float gm = NEG;
            for (int ss = 0; ss < S; ++ss)
                gm = fmaxf(gm, mlw[((size_t)(b * S + ss) * NLQ + q) * 2]);
            float L = 0.f;
            for (int ss = 0; ss < S; ++ss) {
                const float m = mlw[((size_t)(b * S + ss) * NLQ + q) * 2];
                const float l = mlw[((size_t)(b * S + ss) * NLQ + q) * 2 + 1];
                if (m != NEG) L += l * __expf(m - gm);
            }
            for (int ss = 0; ss < S; ++ss) {
                const float m = mlw[((size_t)(b * S + ss) * NLQ + q) * 2];
                const float l = mlw[((size_t)(b * S + ss) * NLQ + q) * 2 + 1];
                fac[tid][ss] = (gm != NEG && L > 0.f && m != NEG)
                             ? l * __expf(m - gm) / L : 0.f;
            }
        } else {
            for (int ss = 0; ss < S; ++ss) fac[tid][ss] = 0.f;
        }
    }
    __syncthreads();

    float sum = 0.f;
    for (int qq = 0; qq < 8; ++qq) {
        const int q = qc * 8 + qq;
        for (int ss = 0; ss < S; ++ss) {
            const float f = fac[qq][ss];
            if (f != 0.f)
                sum += (float)accw[((size_t)(b * S + ss) * NLQ + q) * NDV + tid] * f;
        }
    }
    atomicAdd(&out_[b * NDV + tid], sum * (1.f / NLQ));
}

extern "C" void kernel_launch(void* const* d_in, const int* in_sizes, int n_in,
                              void* d_out, int out_size, void* d_ws, size_t ws_size,
                              hipStream_t stream) {
    const float* q    = (const float*)d_in[0];
    const int*   qlen = (const int*)d_in[1];
    const float* k    = (const float*)d_in[2];
    const float* v    = (const float*)d_in[3];
    const int*   mask = (const int*)d_in[4];
    float* out = (float*)d_out;

    int S = SPLITS;   // auto-halve if ws is small (MK sized for S>=MINSPLITS)
    while (S > MINSPLITS &&
           ((size_t)NB * S * NLQ * NDV * 2 + (size_t)NB * S * NLQ * 8) > ws_size)
        S >>= 1;
    f16*   accw = (f16*)d_ws;
    float* mlw  = (float*)((char*)d_ws + (size_t)NB * S * NLQ * NDV * 2);

    hipMemsetAsync(out, 0, (size_t)out_size * sizeof(float), stream);
    dim3 g1(2 * S, NB);   // x = (s, qz): qz-pairs adjacent in dispatch order
    fvta_part1<<<g1, 512, 0, stream>>>(q, k, v, mask, accw, mlw);
    dim3 g2(NLQ / 8, NB);
    fvta_merge<<<g2, 256, 0, stream>>>(accw, mlw, qlen, out, S);
}